// Round 1
// baseline (268.178 us; speedup 1.0000x reference)
//
#include <hip/hip_runtime.h>
#include <hip/hip_cooperative_groups.h>

#define C_IN   512
#define C_INT  128
#define NBUCK  8192
#define SEG    32
#define NSEG   256   // 8192 / SEG

namespace cg = cooperative_groups;

typedef short short8 __attribute__((ext_vector_type(8)));
typedef float floatx4 __attribute__((ext_vector_type(4)));

// ---------- helpers ----------

// Monotone (after clamp) bucket mapping; identical everywhere it is used.
__device__ __forceinline__ int bucket_of(float v, float bmin, float inv_w) {
    float fk = (v - bmin) * inv_w;
    fk = fminf(fmaxf(fk, 0.f), (float)(NBUCK - 1));
    return (int)fk;
}

// fp32 -> bf16 round-to-nearest-even
__device__ __forceinline__ short bf16rnd(float v) {
    unsigned u = __float_as_uint(v);
    return (short)((u + 0x7fffu + ((u >> 16) & 1u)) >> 16);
}

// order-preserving float<->uint key (for atomicMin/Max on floats)
__device__ __forceinline__ unsigned fkey(float f) {
    unsigned u = __float_as_uint(f);
    return (u & 0x80000000u) ? ~u : (u | 0x80000000u);
}
__device__ __forceinline__ float fdecode(unsigned k) {
    unsigned u = (k & 0x80000000u) ? (k ^ 0x80000000u) : ~k;
    return __uint_as_float(u);
}

// ---------- K1: prep (verified r5) + hist/blocksum zero + minmax key init ----------

__global__ __launch_bounds__(256) void prep_kernel(
        const float* __restrict__ Wt, const float* __restrict__ Wp,
        const float* __restrict__ Wg, const float* __restrict__ wcat,
        const float* __restrict__ bt, const float* __restrict__ bp,
        float* __restrict__ ut, float* __restrict__ up, float* __restrict__ scal,
        unsigned short* __restrict__ WgT,
        unsigned* __restrict__ hist, unsigned* __restrict__ blocksum) {
    int t = threadIdx.x, bk = blockIdx.x;
    if (bk < 16) {
        const float* W  = (bk < 8) ? Wt : Wp;
        const float* wv = wcat + ((bk < 8) ? 0 : C_INT);
        float* dst      = (bk < 8) ? ut : up;
        int k = (bk & 7) * 64 + (t >> 2);
        int q = t & 3;
        const float4* row = (const float4*)(W + (size_t)k * C_INT);
        const float4* cv4 = (const float4*)wv;
        float s = 0.f;
        #pragma unroll
        for (int i = 0; i < 8; ++i) {
            float4 a = row[q * 8 + i];
            float4 c = cv4[q * 8 + i];
            s += a.x * c.x + a.y * c.y + a.z * c.z + a.w * c.w;
        }
        s += __shfl_xor(s, 1);
        s += __shfl_xor(s, 2);
        if (q == 0) dst[k] = s;
    } else if (bk == 16) {
        float s1p = (t < C_INT) ? bt[t] * wcat[t] : 0.f;
        float s2p = (t < C_INT) ? bp[t] * wcat[C_INT + t] : 0.f;
        for (int off = 32; off; off >>= 1) {
            s1p += __shfl_down(s1p, off);
            s2p += __shfl_down(s2p, off);
        }
        __shared__ float red[8];
        int w = t >> 6, lane = t & 63;
        if (lane == 0) { red[w] = s1p; red[4 + w] = s2p; }
        __syncthreads();
        if (t == 0) {
            scal[0] = red[0] + red[1] + red[2] + red[3];
            scal[1] = red[4] + red[5] + red[6] + red[7];
            // init global min/max keys for mid_kernel
            ((unsigned*)scal)[6] = 0xFFFFFFFFu;
            ((unsigned*)scal)[7] = 0u;
        }
    } else if (bk < 25) {
        __shared__ float tile[64][132];
        int kb = (bk - 17) * 64;
        #pragma unroll
        for (int it = 0; it < 8; ++it) {
            int idx = it * 256 + t;
            int r = idx >> 5, c4 = idx & 31;
            *(float4*)&tile[r][c4 * 4] =
                ((const float4*)(Wg + (size_t)(kb + r) * C_INT))[c4];
        }
        __syncthreads();
        int n = t & 127, kc = (t >> 7) * 32;
        unsigned pk[16];
        #pragma unroll
        for (int i = 0; i < 16; ++i) {
            unsigned lo = (unsigned short)bf16rnd(tile[kc + 2 * i][n]);
            unsigned hi = (unsigned short)bf16rnd(tile[kc + 2 * i + 1][n]);
            pk[i] = lo | (hi << 16);
        }
        uint4* dst = (uint4*)(WgT + (size_t)n * C_IN + kb + kc);
        #pragma unroll
        for (int i2 = 0; i2 < 4; ++i2) dst[i2] = *(uint4*)&pk[i2 * 4];
    } else {
        // bk == 25: zero hist (8192 u32) and blocksum (256 u32)
        uint4 z = {0u, 0u, 0u, 0u};
        uint4* h4 = (uint4*)hist;
        #pragma unroll
        for (int i = 0; i < 8; ++i) h4[t + i * 256] = z;
        if (t < 64) ((uint4*)blocksum)[t] = z;
    }
}

// ---------- K2: MFMA gemm, col-split: 1024 blocks x (16 rows x 64 cols), 4-wave K-split ----------
// (unchanged, verified)

#define RSTR 66

__global__ __launch_bounds__(256) void gemm_mfma(
        const float* __restrict__ x, const unsigned short* __restrict__ WgT,
        const float* __restrict__ bg,
        const float* __restrict__ ut, const float* __restrict__ up,
        const float* __restrict__ scal,
        _Float16* __restrict__ g, float* __restrict__ a, float* __restrict__ b) {
    __shared__ float red[3][20][RSTR];
    int tid = threadIdx.x;
    int lane = tid & 63, wv = tid >> 6;
    int bx = blockIdx.x;
    int i0 = (bx >> 1) * 16;
    int cg2 = bx & 1;                 // column group: cols cg2*64 .. cg2*64+63
    int m = lane & 15, q = lane >> 4;
    floatx4 accg[4] = {};
    floatx4 accab = {};
    const float* xrow = x + (size_t)(i0 + m) * C_IN + q * 8;
    const float* absrc = (m == 0) ? ut : up;
    #pragma unroll
    for (int ks = 0; ks < 4; ++ks) {
        int k0 = (wv * 4 + ks) * 32;
        float4 f0 = *(const float4*)(xrow + k0);
        float4 f1 = *(const float4*)(xrow + k0 + 4);
        short8 af;
        af[0] = bf16rnd(f0.x); af[1] = bf16rnd(f0.y);
        af[2] = bf16rnd(f0.z); af[3] = bf16rnd(f0.w);
        af[4] = bf16rnd(f1.x); af[5] = bf16rnd(f1.y);
        af[6] = bf16rnd(f1.z); af[7] = bf16rnd(f1.w);
        if (cg2 == 0) {
            short8 abf = {};
            if (m < 2) {
                float4 u0 = *(const float4*)(absrc + k0 + q * 8);
                float4 u1 = *(const float4*)(absrc + k0 + q * 8 + 4);
                abf[0] = bf16rnd(u0.x); abf[1] = bf16rnd(u0.y);
                abf[2] = bf16rnd(u0.z); abf[3] = bf16rnd(u0.w);
                abf[4] = bf16rnd(u1.x); abf[5] = bf16rnd(u1.y);
                abf[6] = bf16rnd(u1.z); abf[7] = bf16rnd(u1.w);
            }
            accab = __builtin_amdgcn_mfma_f32_16x16x32_bf16(af, abf, accab, 0, 0, 0);
        }
        #pragma unroll
        for (int f = 0; f < 4; ++f) {
            short8 bfr = *(const short8*)(WgT + (size_t)(cg2 * 64 + f * 16 + m) * C_IN + k0 + q * 8);
            accg[f] = __builtin_amdgcn_mfma_f32_16x16x32_bf16(af, bfr, accg[f], 0, 0, 0);
        }
    }
    if (wv) {
        #pragma unroll
        for (int f = 0; f < 4; ++f)
            #pragma unroll
            for (int r = 0; r < 4; ++r)
                red[wv - 1][f * 4 + r][lane] = accg[f][r];
        #pragma unroll
        for (int r = 0; r < 4; ++r)
            red[wv - 1][16 + r][lane] = accab[r];
    }
    __syncthreads();
    if (wv == 0) {
        #pragma unroll
        for (int w = 0; w < 3; ++w) {
            #pragma unroll
            for (int f = 0; f < 4; ++f)
                #pragma unroll
                for (int r = 0; r < 4; ++r)
                    accg[f][r] += red[w][f * 4 + r][lane];
            #pragma unroll
            for (int r = 0; r < 4; ++r)
                accab[r] += red[w][16 + r][lane];
        }
        // epilogue: C layout col = lane&15, row = q*4 + reg
        #pragma unroll
        for (int f = 0; f < 4; ++f) {
            int col = cg2 * 64 + f * 16 + m;
            float bgv = bg[col];
            #pragma unroll
            for (int r = 0; r < 4; ++r) {
                int row = i0 + q * 4 + r;
                g[(size_t)row * C_INT + col] = (_Float16)(accg[f][r] + bgv);
            }
        }
        if (cg2 == 0 && m < 2) {
            float off = m ? scal[1] : scal[0];
            float* dst = m ? b : a;
            #pragma unroll
            for (int r = 0; r < 4; ++r) dst[i0 + q * 4 + r] = accab[r] + off;
        }
    }
}

// ---------- K3 (cooperative): distributed sort + segsum + suffix/Pr in one launch ----------
// 256 blocks x 128 threads, 5 grid syncs. Replaces sort_kernel + segsum_kernel + expand_kernel.

__global__ __launch_bounds__(128) void mid_kernel(
        const float* __restrict__ b, float* __restrict__ scal,
        unsigned* __restrict__ hist, unsigned* __restrict__ offs_g,
        unsigned* __restrict__ blocksum,
        unsigned short* __restrict__ perm_g, float* __restrict__ bsort_g,
        const _Float16* __restrict__ g,
        float* __restrict__ seg1, float* __restrict__ seg2,
        float* __restrict__ Pr1, float* __restrict__ Pr2) {
    cg::grid_group grid = cg::this_grid();
    int s = blockIdx.x, t = threadIdx.x;

    // ---- A0: exact global min/max of b (block reduce + ordered-key atomics) ----
    float bv = 0.f;
    if (t < SEG) {
        bv = b[s * SEG + t];
        float mn = bv, mx = bv;
        #pragma unroll
        for (int d = 16; d; d >>= 1) {
            mn = fminf(mn, __shfl_xor(mn, d));
            mx = fmaxf(mx, __shfl_xor(mx, d));
        }
        if (t == 0) {
            atomicMin(&((unsigned*)scal)[6], fkey(mn));
            atomicMax(&((unsigned*)scal)[7], fkey(mx));
        }
    }
    grid.sync();

    // ---- A: histogram (+ bucket-group sums for the scan base) ----
    float gmn = fdecode(((const unsigned*)scal)[6]);
    float gmx = fdecode(((const unsigned*)scal)[7]);
    float range = gmx - gmn;
    float iw = (range > 1e-30f) ? (float)NBUCK / range : 0.f;
    if (s == 0 && t == 0) { scal[4] = gmn; scal[5] = iw; }   // publish for out_kernel
    int k = 0;
    if (t < SEG) {
        k = bucket_of(bv, gmn, iw);
        atomicAdd(&hist[k], 1u);
        atomicAdd(&blocksum[k >> 5], 1u);
    }
    grid.sync();

    // ---- B: exclusive bucket offsets (one-level distributed scan) ----
    unsigned v = 0;
    if (t < 32) {
        v = hist[s * 32 + t];
        #pragma unroll
        for (int d = 1; d < 32; d <<= 1) {
            unsigned u = __shfl_up(v, d);
            if (t >= d) v += u;
        }
    }
    unsigned base = 0;
    if (t < 64) {
        unsigned acc = 0;
        #pragma unroll
        for (int i = 0; i < 4; ++i) {
            int idx = t + i * 64;
            if (idx < s) acc += blocksum[idx];
        }
        #pragma unroll
        for (int d = 32; d; d >>= 1) acc += __shfl_xor(acc, d);
        base = acc;
    }
    if (t < 32) offs_g[s * 32 + t + 1] = base + v;
    if (s == 0 && t == 0) offs_g[0] = 0u;
    grid.sync();

    // ---- C: scatter (intra-bucket order arbitrary; out_kernel only needs grouping) ----
    if (t < SEG) {
        unsigned st = offs_g[k];
        unsigned pos = atomicSub(&hist[k], 1u) - 1u;   // reuse hist as cursor
        unsigned e = st + pos;
        perm_g[e] = (unsigned short)(s * SEG + t);
        bsort_g[e] = bv;
    }
    grid.sync();

    // ---- D: per-segment sums (g rows cached in registers for phase E) ----
    __shared__ int pj[SEG];
    __shared__ float pb[SEG];
    if (t < SEG) { pj[t] = perm_g[s * SEG + t]; pb[t] = bsort_g[s * SEG + t]; }
    __syncthreads();
    float gv[SEG];
    float a1 = 0.f, a2 = 0.f;
    #pragma unroll
    for (int e = 0; e < SEG; ++e) {
        gv[e] = (float)g[(size_t)pj[e] * C_INT + t];
        a1 += gv[e]; a2 += pb[e] * gv[e];
    }
    seg1[s * C_INT + t] = a1;
    seg2[s * C_INT + t] = a2;
    grid.sync();

    // ---- E: row-granular suffix sums Pr1/Pr2 ----
    float r1 = 0.f, r2 = 0.f;
    #pragma unroll 4
    for (int s2 = s + 1; s2 < NSEG; ++s2) {
        r1 += seg1[s2 * C_INT + t];
        r2 += seg2[s2 * C_INT + t];
    }
    #pragma unroll
    for (int e = SEG - 1; e >= 0; --e) {
        r1 += gv[e]; r2 += pb[e] * gv[e];
        size_t idx = (size_t)(s * SEG + e) * C_INT + t;
        Pr1[idx] = r1; Pr2[idx] = r2;
    }
    if (s == NSEG - 1) {
        Pr1[(size_t)NBUCK * C_INT + t] = 0.f;
        Pr2[(size_t)NBUCK * C_INT + t] = 0.f;
    }
}

// ---------- K4: per-row output: Pr lookup + ~1-row exact tail (verified r7, unchanged) ----------

__global__ __launch_bounds__(128) void out_kernel(
        const float* __restrict__ a, const float* __restrict__ scal,
        const _Float16* __restrict__ g,
        const unsigned* __restrict__ offs, const unsigned short* __restrict__ perm,
        const float* __restrict__ bsort,
        const float* __restrict__ Pr1, const float* __restrict__ Pr2,
        float* __restrict__ out, float inv_n) {
    __shared__ int pj[128];
    __shared__ float pb[128];
    int i = blockIdx.x, c = threadIdx.x;
    float ai = a[i], thr = -ai;
    float bmin = scal[4], inv_w = scal[5];
    int ki = bucket_of(thr, bmin, inv_w);
    unsigned e0 = offs[ki], e1 = offs[ki + 1];
    size_t base = (size_t)e1 * C_INT + c;
    float acc = ai * Pr1[base] + Pr2[base];
    for (unsigned be = e0; be < e1; be += 128) {
        unsigned cnt = min(128u, e1 - be);
        if ((unsigned)c < cnt) { pj[c] = perm[be + c]; pb[c] = bsort[be + c]; }
        __syncthreads();
        for (unsigned r = 0; r < cnt; ++r) {
            float bj = pb[r];
            if (bj > thr)
                acc += (ai + bj) * (float)g[(size_t)pj[r] * C_INT + c];
        }
        __syncthreads();
    }
    out[(size_t)i * C_INT + c] = acc * inv_n;
}

// ---------- launch ----------

extern "C" void kernel_launch(void* const* d_in, const int* in_sizes, int n_in,
                              void* d_out, int out_size, void* d_ws, size_t ws_size,
                              hipStream_t stream) {
    const float* x    = (const float*)d_in[0];
    const float* Wg   = (const float*)d_in[1];
    const float* bg   = (const float*)d_in[2];
    const float* Wt   = (const float*)d_in[3];
    const float* bt   = (const float*)d_in[4];
    const float* Wp   = (const float*)d_in[5];
    const float* bp   = (const float*)d_in[6];
    const float* wcat = (const float*)d_in[7];
    float* out = (float*)d_out;
    int n = in_sizes[0] / C_IN;   // 8192

    char* w = (char*)d_ws;
    size_t off = 0;
    auto alloc = [&](size_t bytes) -> void* {
        void* p = w + off;
        off += (bytes + 255) & ~(size_t)255;
        return p;
    };
    float*          ut    = (float*)alloc(C_IN * 4);
    float*          up    = (float*)alloc(C_IN * 4);
    float*          scal  = (float*)alloc(32);
    float*          a     = (float*)alloc((size_t)n * 4);
    float*          b     = (float*)alloc((size_t)n * 4);
    unsigned*       offs  = (unsigned*)alloc((size_t)(NBUCK + 1) * 4);
    unsigned short* perm  = (unsigned short*)alloc((size_t)n * 2);
    float*          bsort = (float*)alloc((size_t)n * 4);
    _Float16*       g     = (_Float16*)alloc((size_t)n * C_INT * 2);
    unsigned short* WgT   = (unsigned short*)alloc((size_t)C_INT * C_IN * 2);
    float*          seg1  = (float*)alloc((size_t)NSEG * C_INT * 4);
    float*          seg2  = (float*)alloc((size_t)NSEG * C_INT * 4);
    float*          Pr1   = (float*)alloc((size_t)(n + 1) * C_INT * 4);
    float*          Pr2   = (float*)alloc((size_t)(n + 1) * C_INT * 4);
    unsigned*       hist  = (unsigned*)alloc((size_t)NBUCK * 4);
    unsigned*       bsum  = (unsigned*)alloc((size_t)NSEG * 4);

    prep_kernel<<<26, 256, 0, stream>>>(Wt, Wp, Wg, wcat, bt, bp, ut, up, scal,
                                        WgT, hist, bsum);
    gemm_mfma<<<n / 8, 256, 0, stream>>>(x, WgT, bg, ut, up, scal, g, a, b);

    {
        void* margs[12];
        margs[0]  = (void*)&b;
        margs[1]  = (void*)&scal;
        margs[2]  = (void*)&hist;
        margs[3]  = (void*)&offs;
        margs[4]  = (void*)&bsum;
        margs[5]  = (void*)&perm;
        margs[6]  = (void*)&bsort;
        margs[7]  = (void*)&g;
        margs[8]  = (void*)&seg1;
        margs[9]  = (void*)&seg2;
        margs[10] = (void*)&Pr1;
        margs[11] = (void*)&Pr2;
        hipLaunchCooperativeKernel(mid_kernel, dim3(NSEG), dim3(128),
                                   margs, 0, stream);
    }

    out_kernel<<<n, 128, 0, stream>>>(a, scal, g, offs, perm, bsort, Pr1, Pr2,
                                      out, 1.0f / (float)n);
}